// Round 10
// baseline (199.810 us; speedup 1.0000x reference)
//
#include <hip/hip_runtime.h>

#define VN 50000
#define EN 800000
#define CAP 48
#define USH 392           // U plane row stride in ushorts (16B-aligned, 2-way banks)

typedef short short8 __attribute__((ext_vector_type(8)));
typedef float float4v __attribute__((ext_vector_type(4)));

// ws layout in float units
#define WS_GBF   0        // f32[128] gamma ++ beta
#define WS_WHI   128      // ushort[24576] W_full hi, MFMA-B swizzled (K=384)
#define WS_WLO   12416    // ushort[24576] W_full lo
#define WS_POS   24704    // int[50000] per-node fill cursors
#define WS_REC   74704    // A: uint4[50000*48] {src,aphi,tphi,0} ; B: int[50000*48]
#define WS_A_BYTES ((size_t)(74704 + 50000 * 48 * 4) * 4)   // 38.7 MB

__device__ __forceinline__ float bf2f(unsigned short u) {
    return __uint_as_float(((unsigned int)u) << 16);
}
__device__ __forceinline__ unsigned short f2bf(float f) {
    unsigned int x = __float_as_uint(f);
    return (unsigned short)((x + 0x7fffu + ((x >> 16) & 1u)) >> 16);  // RNE
}
__device__ __forceinline__ float ldf(const void* p, int isbf, size_t i) {
    return isbf ? bf2f(((const unsigned short*)p)[i]) : ((const float*)p)[i];
}

// per-block dtype detect from x's bit pattern
__device__ __forceinline__ int block_detect(const void* xv) {
    __shared__ int flg;
    if (threadIdx.x < 64) {
        unsigned short w = ((const unsigned short*)xv)[2 * threadIdx.x];
        int e = (w >> 7) & 0xFF;
        bool ok = (e >= 0x70 && e <= 0x85) || (w == 0);
        unsigned long long m = __ballot(ok);
        if (threadIdx.x == 0) flg = (__popcll(m) >= 40) ? 1 : 0;
    }
    __syncthreads();
    return flg;
}

// W_full[k][n] = (k<320) ? W_neigh[k>>6][n][k&63] : K_self[n][k-320]
__device__ __forceinline__ void convert_dev(int idx, const void* Ks,
                                            const void* Wn, const void* gma,
                                            const void* bta, float* ws, int isbf) {
    if (idx < 128) {
        const void* p = (idx < 64) ? gma : bta;
        ws[WS_GBF + idx] = ldf(p, isbf, idx & 63);
    } else {
        int m2 = idx - 128;               // < 24576
        int j = m2 & 7;
        int chunk = m2 >> 3;
        int slot = chunk >> 6;
        int ln = chunk & 63;
        int ks = slot >> 2, wv = slot & 3;
        int k = ks * 32 + ((ln >> 4) * 8) + j;
        int n = wv * 16 + (ln & 15);
        float wvl;
        if (k < 320) {
            int b = k >> 6, i = k & 63;
            wvl = ldf(Wn, isbf, (b * 64 + n) * 64 + i);
        } else {
            wvl = ldf(Ks, isbf, n * 64 + (k - 320));
        }
        unsigned short hi = f2bf(wvl);
        unsigned short lo = f2bf(wvl - bf2f(hi));
        ((unsigned short*)(ws + WS_WHI))[m2] = hi;
        ((unsigned short*)(ws + WS_WLO))[m2] = lo;
    }
}

// ---------------------------------------------------------------------------
// conv_place: weight canonicalization + padded-CSR placement, one dispatch.
// ---------------------------------------------------------------------------
template <bool PAY>
__global__ __launch_bounds__(512) void conv_place(
    const void* xv, const int* __restrict__ eidx, const void* angv,
    const void* trpv, const void* Ks, const void* Wn, const void* gma,
    const void* bta, float* __restrict__ ws) {
    const int isbf = block_detect(xv);
    int gtid = blockIdx.x * 512 + threadIdx.x;
    if (gtid < 128 + 24576) convert_dev(gtid, Ks, Wn, gma, bta, ws, isbf);
    if (gtid < EN) {
        int tgt = eidx[EN + gtid];
        int slot = atomicAdd(&((int*)(ws + WS_POS))[tgt], 1);
        if (slot < CAP) {
            if (PAY) {
                uint4 r;
                r.x = (unsigned int)eidx[gtid];
                r.y = __float_as_uint(ldf(angv, isbf, gtid));
                r.z = __float_as_uint(ldf(trpv, isbf, gtid));
                r.w = 0u;
                ((uint4*)(ws + WS_REC))[(size_t)tgt * CAP + slot] = r;
            } else {
                ((int*)(ws + WS_REC))[(size_t)tgt * CAP + slot] = gtid;
            }
        }
    }
}

// ---------------------------------------------------------------------------
// gem: 512 thr = 8 waves = 8 nodes/block, 4 blocks/CU (LDS ~37KB) -> 4
// independent barrier domains per CU (r9 had 2), shorter deg-tails.
//  ph0: per-edge trig -> Ledge 16-float records with PRE-SELECTED per-lane-
//       group slots: [0..3]={src,ca,sa,c2a} [4+4g..]={cl,sl,s2a,0} for
//       g=0(id),1(rot phi),2(rot 2phi) -> ph1 needs no cndmask/recompute.
//  ph1: node per wave; software-pipelined x-gathers (prefetch next 4 rows).
//  ph2 (waves 0-3): K=384 matvec, 3 MFMAs/ks (split-bf16), A rows clamped &7.
//  ph3: LN + gated nonlinearity + residual.
// ---------------------------------------------------------------------------
template <bool BF, bool PAY>
__device__ __forceinline__ void gem_body(
    const void* xv, const int* __restrict__ eidx, const void* angv,
    const void* trpv, const float* __restrict__ ws, void* __restrict__ outv,
    float* Ledge, unsigned short* Uhi, unsigned short* Ulo) {
    const int t = threadIdx.x;
    const int lane = t & 63;
    const int w = t >> 6;                   // 0..7 = node row
    const int v0 = blockIdx.x * 8;
    const int* pos = (const int*)(ws + WS_POS);
    float* Cst = Ledge;                     // alias (ph1 data dead by ph2)

    // ---- ph0: trig, one thread per (node,slot) ----------------------------
    if (t < 8 * CAP) {
        int n = t / CAP, s = t - n * CAP;
        int dn = min(pos[v0 + n], CAP);
        if (s < dn) {
            unsigned int srcb;
            float aphi, tphi;
            if (PAY) {
                uint4 r = ((const uint4*)(ws + WS_REC))[(size_t)(v0 + n) * CAP + s];
                srcb = r.x;
                aphi = __uint_as_float(r.y);
                tphi = __uint_as_float(r.z);
            } else {
                int e = ((const int*)(ws + WS_REC))[(size_t)(v0 + n) * CAP + s];
                srcb = (unsigned int)eidx[e];
                aphi = BF ? bf2f(((const unsigned short*)angv)[e])
                          : ((const float*)angv)[e];
                tphi = BF ? bf2f(((const unsigned short*)trpv)[e])
                          : ((const float*)trpv)[e];
            }
            float st, ct, sa, ca;
            __sincosf(tphi, &st, &ct);
            __sincosf(aphi, &sa, &ca);
            float c2a = fmaf(ca, ca, -sa * sa), s2a = 2.f * ca * sa;
            float c2t = fmaf(ct, ct, -st * st), s2t = 2.f * ct * st;
            float* L = &Ledge[t * 16];
            *(float4v*)(L)      = (float4v){__uint_as_float(srcb), ca, sa, c2a};
            *(float4v*)(L + 4)  = (float4v){1.f, 0.f, s2a, 0.f};
            *(float4v*)(L + 8)  = (float4v){ct, st, s2a, 0.f};
            *(float4v*)(L + 12) = (float4v){c2t, s2t, s2a, 0.f};
        }
    }
    __syncthreads();

    // ---- ph1: node v = v0 + w ---------------------------------------------
    const int v = v0 + w;
    const int d = min(pos[v], CAP);
    const int g = (lane < 16) ? 0 : ((lane < 48) ? 1 : 2);
    const int grpoff = 4 + 4 * g;
    const unsigned int smask = (lane & 1) ? 0u : 0x80000000u;
    float a0 = 0.f, a1 = 0.f, a2 = 0.f, a3 = 0.f, a4 = 0.f;

    const float* Lb = &Ledge[w * CAP * 16];
    auto loadx = [&](unsigned int s) -> float {
        if (BF) return bf2f(((const unsigned short*)xv)[(size_t)s * 64 + lane]);
        else    return ((const float*)xv)[(size_t)s * 64 + lane];
    };
    auto edge1 = [&](int j, float xg) {
        const float* L = &Lb[j * 16];
        float4v sh = *(const float4v*)L;          // {src, ca, sa, c2a}
        float4v gr = *(const float4v*)(L + grpoff);  // {cl, sl, s2a, 0}
        float prt = __shfl_xor(xg, 1, 64);
        float tmp = __uint_as_float(__float_as_uint(gr[1] * prt) ^ smask);
        float fq = fmaf(gr[0], xg, tmp);
        a0 += fq;
        a1 = fmaf(sh[1], fq, a1);
        a2 = fmaf(sh[2], fq, a2);
        a3 = fmaf(sh[3], fq, a3);
        a4 = fmaf(gr[2], fq, a4);
    };

    const int nb = d >> 2;
    float y0, y1, y2, y3;
    if (nb > 0) {
        y0 = loadx(__float_as_uint(Lb[0 * 16]));
        y1 = loadx(__float_as_uint(Lb[1 * 16]));
        y2 = loadx(__float_as_uint(Lb[2 * 16]));
        y3 = loadx(__float_as_uint(Lb[3 * 16]));
    }
    for (int b = 0; b < nb; ++b) {
        float z0, z1, z2, z3;
        const bool more = (b + 1 < nb);
        if (more) {
            int j4 = (b + 1) * 4;
            z0 = loadx(__float_as_uint(Lb[(j4 + 0) * 16]));
            z1 = loadx(__float_as_uint(Lb[(j4 + 1) * 16]));
            z2 = loadx(__float_as_uint(Lb[(j4 + 2) * 16]));
            z3 = loadx(__float_as_uint(Lb[(j4 + 3) * 16]));
        }
        int j0 = b * 4;
        edge1(j0 + 0, y0); edge1(j0 + 1, y1);
        edge1(j0 + 2, y2); edge1(j0 + 3, y3);
        if (more) { y0 = z0; y1 = z1; y2 = z2; y3 = z3; }
    }
    for (int j = nb * 4; j < d; ++j)
        edge1(j, loadx(__float_as_uint(Lb[j * 16])));

    float xown = BF ? bf2f(((const unsigned short*)xv)[(size_t)v * 64 + lane])
                    : ((const float*)xv)[(size_t)v * 64 + lane];
    auto wrU = [&](int c, float val) {
        unsigned short h = f2bf(val);
        unsigned short l = f2bf(val - bf2f(h));
        Uhi[w * USH + c * 64 + lane] = h;
        Ulo[w * USH + c * 64 + lane] = l;
    };
    wrU(0, a0); wrU(1, a1); wrU(2, a2); wrU(3, a3); wrU(4, a4); wrU(5, xown);
    __syncthreads();

    // ---- ph2: waves 0..3, K=384 matvec, 3 MFMAs/ks ------------------------
    const int mcol = lane & 15, q = lane >> 4;
    if (w < 4) {
        const int mrow = mcol & 7;          // rows 8-15 mirror 0-7 (discarded)
        const unsigned short* Whi = (const unsigned short*)(ws + WS_WHI);
        const unsigned short* Wlo = (const unsigned short*)(ws + WS_WLO);
        float4v acc = (float4v){0.f, 0.f, 0.f, 0.f};
#pragma unroll
        for (int ks = 0; ks < 12; ++ks) {
            short8 ahi = *(const short8*)&Uhi[mrow * USH + ks * 32 + q * 8];
            short8 alo = *(const short8*)&Ulo[mrow * USH + ks * 32 + q * 8];
            short8 bhi = *(const short8*)(Whi + ((size_t)(ks * 4 + w) * 64 + lane) * 8);
            short8 blo = *(const short8*)(Wlo + ((size_t)(ks * 4 + w) * 64 + lane) * 8);
            acc = __builtin_amdgcn_mfma_f32_16x16x32_bf16(ahi, bhi, acc, 0, 0, 0);
            acc = __builtin_amdgcn_mfma_f32_16x16x32_bf16(alo, bhi, acc, 0, 0, 0);
            acc = __builtin_amdgcn_mfma_f32_16x16x32_bf16(ahi, blo, acc, 0, 0, 0);
        }
#pragma unroll
        for (int reg = 0; reg < 4; ++reg)
            Cst[(q * 4 + reg) * 68 + w * 16 + mcol] = acc[reg];
    }
    __syncthreads();

    // ---- ph3: LN + gated nonlinearity + residual --------------------------
    const float* gbf = ws + WS_GBF;
    float s = Cst[w * 68 + lane];
    float s1 = s, s2v = s * s;
#pragma unroll
    for (int off = 32; off > 0; off >>= 1) {
        s1 += __shfl_xor(s1, off, 64);
        s2v += __shfl_xor(s2v, off, 64);
    }
    float mu = s1 * (1.f / 64.f);
    float var = s2v * (1.f / 64.f) - mu * mu;
    float h = (s - mu) * rsqrtf(var + 1e-5f) * gbf[lane] + gbf[64 + lane];

    float prt = __shfl_xor(h, 1, 64);
    float rlt;
    if (lane < 16) {
        rlt = fmaxf(h, 0.f);
    } else {
        float nrm = sqrtf(h * h + prt * prt);
        nrm = fmaxf(nrm, 1e-8f);
        float sp = (nrm > 20.f) ? nrm : log1pf(__expf(nrm));
        rlt = h * (sp / nrm);
    }
    float xr = bf2f(Uhi[w * USH + 320 + lane]) + bf2f(Ulo[w * USH + 320 + lane]);
    float res = rlt + xr;
    if (BF) ((unsigned short*)outv)[(size_t)v * 64 + lane] = f2bf(res);
    else    ((float*)outv)[(size_t)v * 64 + lane] = res;
}

template <bool PAY>
__global__ __launch_bounds__(512, 8) void gem_kernel(
    const void* xv, const int* __restrict__ eidx, const void* angv,
    const void* trpv, const float* __restrict__ ws, void* __restrict__ outv) {
    // LDS hoisted here: shared between BF instantiations (~37 KB total)
    __shared__ float Ledge[8 * CAP * 16];        // 24.6 KB (ph2/3: Cst alias)
    __shared__ unsigned short Uhi[8 * USH];      // 6.3 KB
    __shared__ unsigned short Ulo[8 * USH];      // 6.3 KB

    const int isbf = block_detect(xv);
    if (isbf) gem_body<true, PAY>(xv, eidx, angv, trpv, ws, outv, Ledge, Uhi, Ulo);
    else      gem_body<false, PAY>(xv, eidx, angv, trpv, ws, outv, Ledge, Uhi, Ulo);
}

extern "C" void kernel_launch(void* const* d_in, const int* in_sizes, int n_in,
                              void* d_out, int out_size, void* d_ws, size_t ws_size,
                              hipStream_t stream) {
    const void* x   = d_in[0];
    const int* eidx = (const int*)d_in[1];
    const void* ang = d_in[2];
    const void* trp = d_in[3];
    const void* Ks  = d_in[4];
    const void* Wn  = d_in[5];
    const void* gma = d_in[6];
    const void* bta = d_in[7];
    float* ws = (float*)d_ws;

    hipMemsetAsync(ws + WS_POS, 0, VN * sizeof(int), stream);
    if (ws_size >= WS_A_BYTES) {
        conv_place<true><<<1563, 512, 0, stream>>>(x, eidx, ang, trp, Ks, Wn,
                                                   gma, bta, ws);
        gem_kernel<true><<<VN / 8, 512, 0, stream>>>(x, eidx, ang, trp, ws,
                                                     d_out);
    } else {
        conv_place<false><<<1563, 512, 0, stream>>>(x, eidx, ang, trp, Ks, Wn,
                                                    gma, bta, ws);
        gem_kernel<false><<<VN / 8, 512, 0, stream>>>(x, eidx, ang, trp, ws,
                                                      d_out);
    }
}

// Round 11
// 197.523 us; speedup vs baseline: 1.0116x; 1.0116x over previous
//
#include <hip/hip_runtime.h>

#define VN 50000
#define EN 800000
#define CAP 48
#define USH 392           // U plane row stride in ushorts (16B-aligned)
#define LREC 12           // Ledge record stride in floats (3 mod 8 quads: conflict-free)

typedef short short8 __attribute__((ext_vector_type(8)));
typedef float float4v __attribute__((ext_vector_type(4)));

// ws layout in float units
#define WS_GBF   0        // f32[128] gamma ++ beta
#define WS_WHI   128      // ushort[24576] W_full hi, MFMA-B swizzled (K=384)
#define WS_WLO   12416    // ushort[24576] W_full lo
#define WS_POS   24704    // int[50000] per-node fill cursors
#define WS_REC   74704    // A: uint4[50000*48] {src,aphi,tphi,0} ; B: int[50000*48]
#define WS_A_BYTES ((size_t)(74704 + 50000 * 48 * 4) * 4)   // 38.7 MB

__device__ __forceinline__ float bf2f(unsigned short u) {
    return __uint_as_float(((unsigned int)u) << 16);
}
__device__ __forceinline__ unsigned short f2bf(float f) {
    unsigned int x = __float_as_uint(f);
    return (unsigned short)((x + 0x7fffu + ((x >> 16) & 1u)) >> 16);  // RNE
}
__device__ __forceinline__ float ldf(const void* p, int isbf, size_t i) {
    return isbf ? bf2f(((const unsigned short*)p)[i]) : ((const float*)p)[i];
}

// per-block dtype detect from x's bit pattern
__device__ __forceinline__ int block_detect(const void* xv) {
    __shared__ int flg;
    if (threadIdx.x < 64) {
        unsigned short w = ((const unsigned short*)xv)[2 * threadIdx.x];
        int e = (w >> 7) & 0xFF;
        bool ok = (e >= 0x70 && e <= 0x85) || (w == 0);
        unsigned long long m = __ballot(ok);
        if (threadIdx.x == 0) flg = (__popcll(m) >= 40) ? 1 : 0;
    }
    __syncthreads();
    return flg;
}

// W_full[k][n] = (k<320) ? W_neigh[k>>6][n][k&63] : K_self[n][k-320]
__device__ __forceinline__ void convert_dev(int idx, const void* Ks,
                                            const void* Wn, const void* gma,
                                            const void* bta, float* ws, int isbf) {
    if (idx < 128) {
        const void* p = (idx < 64) ? gma : bta;
        ws[WS_GBF + idx] = ldf(p, isbf, idx & 63);
    } else {
        int m2 = idx - 128;               // < 24576
        int j = m2 & 7;
        int chunk = m2 >> 3;
        int slot = chunk >> 6;
        int ln = chunk & 63;
        int ks = slot >> 2, wv = slot & 3;
        int k = ks * 32 + ((ln >> 4) * 8) + j;
        int n = wv * 16 + (ln & 15);
        float wvl;
        if (k < 320) {
            int b = k >> 6, i = k & 63;
            wvl = ldf(Wn, isbf, (b * 64 + n) * 64 + i);
        } else {
            wvl = ldf(Ks, isbf, n * 64 + (k - 320));
        }
        unsigned short hi = f2bf(wvl);
        unsigned short lo = f2bf(wvl - bf2f(hi));
        ((unsigned short*)(ws + WS_WHI))[m2] = hi;
        ((unsigned short*)(ws + WS_WLO))[m2] = lo;
    }
}

// ---------------------------------------------------------------------------
// conv_place: weight canonicalization + padded-CSR placement, one dispatch.
// ---------------------------------------------------------------------------
template <bool PAY>
__global__ __launch_bounds__(512) void conv_place(
    const void* xv, const int* __restrict__ eidx, const void* angv,
    const void* trpv, const void* Ks, const void* Wn, const void* gma,
    const void* bta, float* __restrict__ ws) {
    const int isbf = block_detect(xv);
    int gtid = blockIdx.x * 512 + threadIdx.x;
    if (gtid < 128 + 24576) convert_dev(gtid, Ks, Wn, gma, bta, ws, isbf);
    if (gtid < EN) {
        int tgt = eidx[EN + gtid];
        int slot = atomicAdd(&((int*)(ws + WS_POS))[tgt], 1);
        if (slot < CAP) {
            if (PAY) {
                uint4 r;
                r.x = (unsigned int)eidx[gtid];
                r.y = __float_as_uint(ldf(angv, isbf, gtid));
                r.z = __float_as_uint(ldf(trpv, isbf, gtid));
                r.w = 0u;
                ((uint4*)(ws + WS_REC))[(size_t)tgt * CAP + slot] = r;
            } else {
                ((int*)(ws + WS_REC))[(size_t)tgt * CAP + slot] = gtid;
            }
        }
    }
}

// ---------------------------------------------------------------------------
// gem: 512 thr = 8 waves = 8 nodes/block (4 blocks/CU, 32 waves = wave cap).
//  ph0: per-edge trig -> 12-float records {src,ca,sa,c2a | ct,st,c2t,s2t}
//       (stride-12 float4 writes hit all 32 banks per 8 lanes: conflict-free).
//       Slots [deg,CAP) zero-padded (valid self-src, zero trig).
//  ph1: node per wave; DEPTH-2 software pipeline: 8 x-row gathers in flight
//       (r10's depth-1/4-deep left waves stalled ~900cyc L3 latency per iter).
//  ph2: ALL 8 waves: slab = w&3, K-half = w>>2 (ks 0-5 / 6-11), partial C
//       planes summed in ph3.
//  ph3: LN + gated nonlinearity + residual.
// ---------------------------------------------------------------------------
template <bool BF, bool PAY>
__device__ __forceinline__ void gem_body(
    const void* xv, const int* __restrict__ eidx, const void* angv,
    const void* trpv, const float* __restrict__ ws, void* __restrict__ outv,
    float* Ledge, unsigned short* Uhi, unsigned short* Ulo) {
    const int t = threadIdx.x;
    const int lane = t & 63;
    const int w = t >> 6;                   // 0..7 = node row
    const int v0 = blockIdx.x * 8;
    const int* pos = (const int*)(ws + WS_POS);
    float* Cst = Ledge;                     // alias: 2 planes of 16x68 floats

    // ---- ph0: trig, one thread per (node,slot); pads zeroed ---------------
    if (t < 8 * CAP) {
        int n = t / CAP, s = t - n * CAP;
        int dn = min(pos[v0 + n], CAP);
        float* L = &Ledge[t * LREC];
        if (s < dn) {
            unsigned int srcb;
            float aphi, tphi;
            if (PAY) {
                uint4 r = ((const uint4*)(ws + WS_REC))[(size_t)(v0 + n) * CAP + s];
                srcb = r.x;
                aphi = __uint_as_float(r.y);
                tphi = __uint_as_float(r.z);
            } else {
                int e = ((const int*)(ws + WS_REC))[(size_t)(v0 + n) * CAP + s];
                srcb = (unsigned int)eidx[e];
                aphi = BF ? bf2f(((const unsigned short*)angv)[e])
                          : ((const float*)angv)[e];
                tphi = BF ? bf2f(((const unsigned short*)trpv)[e])
                          : ((const float*)trpv)[e];
            }
            float st, ct, sa, ca;
            __sincosf(tphi, &st, &ct);
            __sincosf(aphi, &sa, &ca);
            *(float4v*)(L)     = (float4v){__uint_as_float(srcb), ca, sa,
                                           fmaf(ca, ca, -sa * sa)};
            *(float4v*)(L + 4) = (float4v){ct, st, fmaf(ct, ct, -st * st),
                                           2.f * ct * st};
        } else {
            *(float4v*)(L)     = (float4v){__uint_as_float((unsigned)(v0 + n)),
                                           0.f, 0.f, 0.f};
            *(float4v*)(L + 4) = (float4v){0.f, 0.f, 0.f, 0.f};
        }
    }
    __syncthreads();

    // ---- ph1: node v = v0 + w, depth-2 pipelined gathers ------------------
    const int v = v0 + w;
    const int d = min(pos[v], CAP);
    const int R = (d + 3) >> 2;             // rounds of 4 (pads make them full)
    const int g = (lane < 16) ? 0 : ((lane < 48) ? 1 : 2);
    const unsigned int smask = (lane & 1) ? 0u : 0x80000000u;
    float a0 = 0.f, a1 = 0.f, a2 = 0.f, a3 = 0.f, a4 = 0.f;

    const float* Lb = &Ledge[w * CAP * LREC];
    auto srcOf = [&](int j) { return __float_as_uint(Lb[j * LREC]); };
    auto loadx = [&](unsigned int s) -> float {
        if (BF) return bf2f(((const unsigned short*)xv)[(size_t)s * 64 + lane]);
        else    return ((const float*)xv)[(size_t)s * 64 + lane];
    };
    auto edge1 = [&](int j, float xg) {
        const float* L = &Lb[j * LREC];
        float4v sh = *(const float4v*)L;          // {src, ca, sa, c2a}
        float4v rt = *(const float4v*)(L + 4);    // {ct, st, c2t, s2t}
        float cl = (g == 0) ? 1.f : ((g == 1) ? rt[0] : rt[2]);
        float sl = (g == 0) ? 0.f : ((g == 1) ? rt[1] : rt[3]);
        float prt = __shfl_xor(xg, 1, 64);
        float tmp = __uint_as_float(__float_as_uint(sl * prt) ^ smask);
        float fq = fmaf(cl, xg, tmp);
        a0 += fq;
        a1 = fmaf(sh[1], fq, a1);
        a2 = fmaf(sh[2], fq, a2);
        a3 = fmaf(sh[3], fq, a3);
        a4 = fmaf(2.f * sh[1] * sh[2], fq, a4);
    };

    float y[4], z[4];
#pragma unroll
    for (int u = 0; u < 4; ++u) y[u] = (R > 0) ? loadx(srcOf(u)) : 0.f;
#pragma unroll
    for (int u = 0; u < 4; ++u) z[u] = (R > 1) ? loadx(srcOf(4 + u)) : 0.f;

    for (int b = 0; b < R; ++b) {
        float nx[4] = {0.f, 0.f, 0.f, 0.f};
        if (b + 2 < R) {
            int j8 = (b + 2) * 4;
#pragma unroll
            for (int u = 0; u < 4; ++u) nx[u] = loadx(srcOf(j8 + u));
        }
        int j0 = b * 4;
#pragma unroll
        for (int u = 0; u < 4; ++u)
            edge1(j0 + u, (j0 + u < d) ? y[u] : 0.f);
#pragma unroll
        for (int u = 0; u < 4; ++u) { y[u] = z[u]; z[u] = nx[u]; }
    }

    float xown = BF ? bf2f(((const unsigned short*)xv)[(size_t)v * 64 + lane])
                    : ((const float*)xv)[(size_t)v * 64 + lane];
    auto wrU = [&](int c, float val) {
        unsigned short h = f2bf(val);
        unsigned short l = f2bf(val - bf2f(h));
        Uhi[w * USH + c * 64 + lane] = h;
        Ulo[w * USH + c * 64 + lane] = l;
    };
    wrU(0, a0); wrU(1, a1); wrU(2, a2); wrU(3, a3); wrU(4, a4); wrU(5, xown);
    __syncthreads();

    // ---- ph2: all 8 waves; slab = w&3, K-half = w>>2 ----------------------
    const int mcol = lane & 15, q = lane >> 4;
    {
        const int slab = w & 3, kh = w >> 2;
        const int mrow = mcol & 7;          // rows 8-15 mirror 0-7 (discarded)
        const unsigned short* Whi = (const unsigned short*)(ws + WS_WHI);
        const unsigned short* Wlo = (const unsigned short*)(ws + WS_WLO);
        float4v acc = (float4v){0.f, 0.f, 0.f, 0.f};
#pragma unroll
        for (int kk = 0; kk < 6; ++kk) {
            const int ks = kh * 6 + kk;
            short8 ahi = *(const short8*)&Uhi[mrow * USH + ks * 32 + q * 8];
            short8 alo = *(const short8*)&Ulo[mrow * USH + ks * 32 + q * 8];
            short8 bhi = *(const short8*)(Whi + ((size_t)(ks * 4 + slab) * 64 + lane) * 8);
            short8 blo = *(const short8*)(Wlo + ((size_t)(ks * 4 + slab) * 64 + lane) * 8);
            acc = __builtin_amdgcn_mfma_f32_16x16x32_bf16(ahi, bhi, acc, 0, 0, 0);
            acc = __builtin_amdgcn_mfma_f32_16x16x32_bf16(alo, bhi, acc, 0, 0, 0);
            acc = __builtin_amdgcn_mfma_f32_16x16x32_bf16(ahi, blo, acc, 0, 0, 0);
        }
#pragma unroll
        for (int reg = 0; reg < 4; ++reg)
            Cst[kh * 1088 + (q * 4 + reg) * 68 + slab * 16 + mcol] = acc[reg];
    }
    __syncthreads();

    // ---- ph3: LN + gated nonlinearity + residual --------------------------
    const float* gbf = ws + WS_GBF;
    float s = Cst[w * 68 + lane] + Cst[1088 + w * 68 + lane];
    float s1 = s, s2v = s * s;
#pragma unroll
    for (int off = 32; off > 0; off >>= 1) {
        s1 += __shfl_xor(s1, off, 64);
        s2v += __shfl_xor(s2v, off, 64);
    }
    float mu = s1 * (1.f / 64.f);
    float var = s2v * (1.f / 64.f) - mu * mu;
    float h = (s - mu) * rsqrtf(var + 1e-5f) * gbf[lane] + gbf[64 + lane];

    float prt = __shfl_xor(h, 1, 64);
    float rlt;
    if (lane < 16) {
        rlt = fmaxf(h, 0.f);
    } else {
        float nrm = sqrtf(h * h + prt * prt);
        nrm = fmaxf(nrm, 1e-8f);
        float sp = (nrm > 20.f) ? nrm : log1pf(__expf(nrm));
        rlt = h * (sp / nrm);
    }
    float xr = bf2f(Uhi[w * USH + 320 + lane]) + bf2f(Ulo[w * USH + 320 + lane]);
    float res = rlt + xr;
    if (BF) ((unsigned short*)outv)[(size_t)v * 64 + lane] = f2bf(res);
    else    ((float*)outv)[(size_t)v * 64 + lane] = res;
}

template <bool PAY>
__global__ __launch_bounds__(512, 8) void gem_kernel(
    const void* xv, const int* __restrict__ eidx, const void* angv,
    const void* trpv, const float* __restrict__ ws, void* __restrict__ outv) {
    // LDS shared between BF instantiations (~31 KB total -> 4 blocks/CU)
    __shared__ float Ledge[8 * CAP * LREC];      // 18.4 KB (ph2/3: Cst alias)
    __shared__ unsigned short Uhi[8 * USH];      // 6.3 KB
    __shared__ unsigned short Ulo[8 * USH];      // 6.3 KB

    const int isbf = block_detect(xv);
    if (isbf) gem_body<true, PAY>(xv, eidx, angv, trpv, ws, outv, Ledge, Uhi, Ulo);
    else      gem_body<false, PAY>(xv, eidx, angv, trpv, ws, outv, Ledge, Uhi, Ulo);
}

extern "C" void kernel_launch(void* const* d_in, const int* in_sizes, int n_in,
                              void* d_out, int out_size, void* d_ws, size_t ws_size,
                              hipStream_t stream) {
    const void* x   = d_in[0];
    const int* eidx = (const int*)d_in[1];
    const void* ang = d_in[2];
    const void* trp = d_in[3];
    const void* Ks  = d_in[4];
    const void* Wn  = d_in[5];
    const void* gma = d_in[6];
    const void* bta = d_in[7];
    float* ws = (float*)d_ws;

    hipMemsetAsync(ws + WS_POS, 0, VN * sizeof(int), stream);
    if (ws_size >= WS_A_BYTES) {
        conv_place<true><<<1563, 512, 0, stream>>>(x, eidx, ang, trp, Ks, Wn,
                                                   gma, bta, ws);
        gem_kernel<true><<<VN / 8, 512, 0, stream>>>(x, eidx, ang, trp, ws,
                                                     d_out);
    } else {
        conv_place<false><<<1563, 512, 0, stream>>>(x, eidx, ang, trp, Ks, Wn,
                                                    gma, bta, ws);
        gem_kernel<false><<<VN / 8, 512, 0, stream>>>(x, eidx, ang, trp, ws,
                                                      d_out);
    }
}